// Round 15
// baseline (482.851 us; speedup 1.0000x reference)
//
#include <hip/hip_runtime.h>
#include <hip/hip_fp16.h>

#define N_VOX 100000
#define KVOL 27
#define MPAIR 50000
#define CIN 64
#define COUT 64
#define TPW 4
#define NTILES 3125              // 50000/16 exact
#define GRIDX 196                // ceil(3125/(4 waves * TPW))
#define NPAIR (KVOL * MPAIR)     // 1,350,000

typedef __attribute__((ext_vector_type(8))) short bf16x8;
typedef __attribute__((ext_vector_type(4))) float f32x4;
typedef __attribute__((ext_vector_type(4))) unsigned short u16x4;

__device__ inline unsigned short f2bf(float f) {  // RNE f32 -> bf16
    union { float f; unsigned u; } v; v.f = f;
    return (unsigned short)((v.u + 0x7FFFu + ((v.u >> 16) & 1u)) >> 16);
}
__device__ inline float bf2f(unsigned short u) {
    union { unsigned u; float f; } v; v.u = (unsigned)u << 16; return v.f;
}

// ---------------- shared helpers ----------------

__global__ void spconv_x_to_bf16(const float* __restrict__ x,
                                 unsigned short* __restrict__ xbf, int n4) {
    int i = blockIdx.x * blockDim.x + threadIdx.x;
    if (i >= n4) return;
    f32x4 v = ((const f32x4*)x)[i];
    u16x4 o; o.x = f2bf(v.x); o.y = f2bf(v.y); o.z = f2bf(v.z); o.w = f2bf(v.w);
    ((u16x4*)xbf)[i] = o;
}

__global__ void spconv_zero_i32(int* __restrict__ p, int n) {
    int i = blockIdx.x * blockDim.x + threadIdx.x;
    if (i < n) p[i] = 0;
}

// ---------------- sorted two-phase path ----------------

// counting-sort allocation: off[i] = my rank within out row
__global__ void spconv_hist_alloc(const int* __restrict__ out_map,
                                  int* __restrict__ cnt,
                                  int* __restrict__ off, int tot) {
    int i = blockIdx.x * blockDim.x + threadIdx.x;
    if (i < tot) off[i] = atomicAdd(&cnt[out_map[i]], 1);
}

// exclusive prefix of cnt[N_VOX] -> rowptr[N_VOX+1], single block
__global__ __launch_bounds__(1024) void spconv_scan(const int* __restrict__ cnt,
                                                    int* __restrict__ rowptr) {
    __shared__ int part[1024];
    const int T = 1024, C = (N_VOX + T - 1) / T;   // 98
    int tid = threadIdx.x;
    int base = tid * C, s = 0;
    for (int j = 0; j < C; ++j) { int idx = base + j; if (idx < N_VOX) s += cnt[idx]; }
    part[tid] = s;
    __syncthreads();
    for (int d = 1; d < T; d <<= 1) {              // Hillis-Steele inclusive
        int v = (tid >= d) ? part[tid - d] : 0;
        __syncthreads();
        part[tid] += v;
        __syncthreads();
    }
    int run = (tid == 0) ? 0 : part[tid - 1];
    for (int j = 0; j < C; ++j) {
        int idx = base + j;
        if (idx < N_VOX) { rowptr[idx] = run; run += cnt[idx]; }
    }
    if (tid == T - 1) rowptr[N_VOX] = run;         // = NPAIR
}

// Phase A: r13-proven gather+MFMA; P (bf16) plain-stored to out-sorted slots.
__global__ __launch_bounds__(256) void spconv_phaseA(
    const unsigned short* __restrict__ xbf,
    const float* __restrict__ kern,
    const int*   __restrict__ in_map,
    const int*   __restrict__ out_map,
    const int*   __restrict__ off,
    const int*   __restrict__ rowptr,
    unsigned short* __restrict__ slots)
{
    const int lane = threadIdx.x & 63;
    const int wave = threadIdx.x >> 6;
    const int k    = blockIdx.y;
    const int g    = lane >> 4;
    const int r16  = lane & 15;
    const int p    = r16 & 1;

    const int tile0 = (blockIdx.x * 4 + wave) * TPW;
    const int base0 = k * MPAIR;

    // in-row indices (lane r16 = row of tile)
    int inrow[TPW];
    #pragma unroll
    for (int t = 0; t < TPW; ++t) {
        int tl = tile0 + t; tl = tl < NTILES ? tl : NTILES - 1;
        inrow[t] = in_map[base0 + tl * 16 + r16];
    }
    // A fragments
    bf16x8 afr[TPW][2];
    #pragma unroll
    for (int t = 0; t < TPW; ++t) {
        const unsigned short* xp = xbf + (size_t)inrow[t] * CIN + g * 8;
        afr[t][0] = *(const bf16x8*)(xp);
        afr[t][1] = *(const bf16x8*)(xp + 32);
    }
    // slot id for pair g*4+(r16&3) of each tile
    int sid_mine[TPW];
    #pragma unroll
    for (int t = 0; t < TPW; ++t) {
        int tl = tile0 + t; tl = tl < NTILES ? tl : NTILES - 1;
        int ip = base0 + tl * 16 + g * 4 + (r16 & 3);
        sid_mine[t] = rowptr[out_map[ip]] + off[ip];
    }
    // B fragments
    bf16x8 bfrag[2][4];
    {
        const float* wp = kern + (size_t)k * CIN * COUT;
        #pragma unroll
        for (int s = 0; s < 2; ++s)
            #pragma unroll
            for (int q = 0; q < 4; ++q) {
                const float* pq = wp + (s * 32 + g * 8) * COUT + q * 16 + r16;
                bf16x8 f;
                #pragma unroll
                for (int j = 0; j < 8; ++j) f[j] = (short)f2bf(pq[j * COUT]);
                bfrag[s][q] = f;
            }
    }
    #pragma unroll
    for (int t = 0; t < TPW; ++t) {
        if (tile0 + t < NTILES) {                  // wave-uniform guard
            f32x4 acc[4] = {{0.f,0.f,0.f,0.f},{0.f,0.f,0.f,0.f},
                            {0.f,0.f,0.f,0.f},{0.f,0.f,0.f,0.f}};
            #pragma unroll
            for (int q = 0; q < 4; ++q) {
                acc[q] = __builtin_amdgcn_mfma_f32_16x16x32_bf16(afr[t][0], bfrag[0][q], acc[q], 0, 0, 0);
                acc[q] = __builtin_amdgcn_mfma_f32_16x16x32_bf16(afr[t][1], bfrag[1][q], acc[q], 0, 0, 0);
            }
            // r7-proven packing, but PLAIN bf16 stores to the pair's slot
            #pragma unroll
            for (int r = 0; r < 4; ++r) {
                int sid = __shfl(sid_mine[t], (lane & 48) + r);
                float pv[4];
                #pragma unroll
                for (int q = 0; q < 4; ++q) pv[q] = __shfl_xor(acc[q][r], 1);
                unsigned* srow = (unsigned*)(slots + (size_t)sid * COUT);
                #pragma unroll
                for (int q2 = 0; q2 < 2; ++q2) {
                    int tt = 2 * p + q2;
                    float lo = p ? pv[tt] : acc[tt][r];
                    float hi = p ? acc[tt][r] : pv[tt];
                    unsigned pk = (unsigned)f2bf(lo) | ((unsigned)f2bf(hi) << 16);
                    int col = tt * 16 + r16 - p;   // even
                    srow[col >> 1] = pk;
                }
            }
        }
    }
}

// Phase B: wave per out row; sum contiguous slot run; +bias; one plain store.
__global__ __launch_bounds__(256) void spconv_phaseB(
    const unsigned short* __restrict__ slots,
    const int*   __restrict__ rowptr,
    const float* __restrict__ bias,
    float*       __restrict__ out)
{
    int w = threadIdx.x >> 6, l = threadIdx.x & 63;
    int o = blockIdx.x * 4 + w;                    // grid 25000 -> o < 100000
    int s0 = rowptr[o], s1 = rowptr[o + 1];
    float acc = 0.f;
    for (int s = s0; s < s1; ++s)
        acc += bf2f(slots[(size_t)s * COUT + l]);
    out[(size_t)o * COUT + l] = acc + bias[l];
}

// ---------------- fallback: proven r13 path (needs 25.6MB) ----------------

__global__ void spconv_zero_ws(__half2* __restrict__ ws, int n2) {
    int i = blockIdx.x * blockDim.x + threadIdx.x;
    if (i < n2) ws[i] = __float2half2_rn(0.f);
}

__global__ void spconv_finalize(const __half2* __restrict__ ws,
                                const float* __restrict__ bias,
                                float* __restrict__ out, int n2) {
    int i = blockIdx.x * blockDim.x + threadIdx.x;
    if (i >= n2) return;
    float2 v = __half22float2(ws[i]);
    int c2 = (i & (COUT / 2 - 1)) * 2;
    float2 o; o.x = v.x + bias[c2]; o.y = v.y + bias[c2 + 1];
    ((float2*)out)[i] = o;
}

__global__ __launch_bounds__(256) void spconv_mlp_f16ws(
    const unsigned short* __restrict__ xbf,
    const float* __restrict__ kern,
    const int*   __restrict__ in_map,
    const int*   __restrict__ out_map,
    __half2*     __restrict__ ws)
{
    const int lane = threadIdx.x & 63;
    const int wave = threadIdx.x >> 6;
    const int k    = blockIdx.y;
    const int g    = lane >> 4;
    const int r16  = lane & 15;
    const int p    = r16 & 1;

    const int tile0 = (blockIdx.x * 4 + wave) * TPW;
    const int base0 = k * MPAIR;

    int inrow[TPW];
    #pragma unroll
    for (int t = 0; t < TPW; ++t) {
        int tl = tile0 + t; tl = tl < NTILES ? tl : NTILES - 1;
        inrow[t] = in_map[base0 + tl * 16 + r16];
    }
    bf16x8 afr[TPW][2];
    #pragma unroll
    for (int t = 0; t < TPW; ++t) {
        const unsigned short* xp = xbf + (size_t)inrow[t] * CIN + g * 8;
        afr[t][0] = *(const bf16x8*)(xp);
        afr[t][1] = *(const bf16x8*)(xp + 32);
    }
    int orow[TPW][4];
    #pragma unroll
    for (int t = 0; t < TPW; ++t) {
        int tl = tile0 + t; tl = tl < NTILES ? tl : NTILES - 1;
        #pragma unroll
        for (int r = 0; r < 4; ++r)
            orow[t][r] = out_map[base0 + tl * 16 + g * 4 + r];
    }
    bf16x8 bfrag[2][4];
    {
        const float* wp = kern + (size_t)k * CIN * COUT;
        #pragma unroll
        for (int s = 0; s < 2; ++s)
            #pragma unroll
            for (int q = 0; q < 4; ++q) {
                const float* pq = wp + (s * 32 + g * 8) * COUT + q * 16 + r16;
                bf16x8 f;
                #pragma unroll
                for (int j = 0; j < 8; ++j) f[j] = (short)f2bf(pq[j * COUT]);
                bfrag[s][q] = f;
            }
    }
    #pragma unroll
    for (int t = 0; t < TPW; ++t) {
        if (tile0 + t < NTILES) {
            f32x4 acc[4] = {{0.f,0.f,0.f,0.f},{0.f,0.f,0.f,0.f},
                            {0.f,0.f,0.f,0.f},{0.f,0.f,0.f,0.f}};
            #pragma unroll
            for (int q = 0; q < 4; ++q) {
                acc[q] = __builtin_amdgcn_mfma_f32_16x16x32_bf16(afr[t][0], bfrag[0][q], acc[q], 0, 0, 0);
                acc[q] = __builtin_amdgcn_mfma_f32_16x16x32_bf16(afr[t][1], bfrag[1][q], acc[q], 0, 0, 0);
            }
            #pragma unroll
            for (int r = 0; r < 4; ++r) {
                float pv[4];
                #pragma unroll
                for (int q = 0; q < 4; ++q) pv[q] = __shfl_xor(acc[q][r], 1);
                __half2* wrow = ws + (size_t)orow[t][r] * (COUT / 2);
                #pragma unroll
                for (int q2 = 0; q2 < 2; ++q2) {
                    int tt = 2 * p + q2;
                    float lo = p ? pv[tt] : acc[tt][r];
                    float hi = p ? acc[tt][r] : pv[tt];
                    int col = tt * 16 + r16 - p;
                    unsafeAtomicAdd(wrow + (col >> 1), __floats2half2_rn(lo, hi));
                }
            }
        }
    }
}

// ---------------- launcher ----------------

static inline size_t al256(size_t a) { return (a + 255) & ~(size_t)255; }

extern "C" void kernel_launch(void* const* d_in, const int* in_sizes, int n_in,
                              void* d_out, int out_size, void* d_ws, size_t ws_size,
                              hipStream_t stream) {
    const float* x       = (const float*)d_in[0];
    const float* kern    = (const float*)d_in[1];
    const float* bias    = (const float*)d_in[2];
    const int*   in_map  = (const int*)d_in[3];
    const int*   out_map = (const int*)d_in[4];
    float*       out     = (float*)d_out;

    const size_t xbf_b   = (size_t)N_VOX * CIN * 2;          // 12.8 MB
    const size_t cnt_b   = (size_t)(N_VOX + 1) * 4;
    const size_t rp_b    = (size_t)(N_VOX + 1) * 4;
    const size_t off_b   = (size_t)NPAIR * 4;                // 5.4 MB
    const size_t slots_b = (size_t)NPAIR * COUT * 2;         // 172.8 MB

    size_t o_xbf = 0;
    size_t o_cnt = al256(o_xbf + xbf_b);
    size_t o_rp  = al256(o_cnt + cnt_b);
    size_t o_off = al256(o_rp + rp_b);
    size_t o_sl  = al256(o_off + off_b);
    size_t need  = o_sl + slots_b;                           // ~191.6 MB

    int n4 = N_VOX * CIN / 4;
    int n2 = N_VOX * COUT / 2;
    dim3 gridA(GRIDX, KVOL);                                 // 196 x 27

    if (ws_size >= need) {
        unsigned short* xbf   = (unsigned short*)((char*)d_ws + o_xbf);
        int*            cnt   = (int*)((char*)d_ws + o_cnt);
        int*            rowp  = (int*)((char*)d_ws + o_rp);
        int*            off   = (int*)((char*)d_ws + o_off);
        unsigned short* slots = (unsigned short*)((char*)d_ws + o_sl);

        spconv_x_to_bf16<<<(n4 + 255) / 256, 256, 0, stream>>>(x, xbf, n4);
        spconv_zero_i32<<<(N_VOX + 1 + 255) / 256, 256, 0, stream>>>(cnt, N_VOX + 1);
        spconv_hist_alloc<<<(NPAIR + 255) / 256, 256, 0, stream>>>(out_map, cnt, off, NPAIR);
        spconv_scan<<<1, 1024, 0, stream>>>(cnt, rowp);
        spconv_phaseA<<<gridA, 256, 0, stream>>>(xbf, kern, in_map, out_map, off, rowp, slots);
        spconv_phaseB<<<N_VOX / 4, 256, 0, stream>>>(slots, rowp, bias, out);
    } else {
        // proven r13 path (25.6 MB)
        unsigned short* xbf = (unsigned short*)d_ws;
        __half2* ws = (__half2*)((char*)d_ws + xbf_b);
        spconv_x_to_bf16<<<(n4 + 255) / 256, 256, 0, stream>>>(x, xbf, n4);
        spconv_zero_ws<<<(n2 + 255) / 256, 256, 0, stream>>>(ws, n2);
        spconv_mlp_f16ws<<<gridA, 256, 0, stream>>>(xbf, kern, in_map, out_map, ws);
        spconv_finalize<<<(n2 + 255) / 256, 256, 0, stream>>>(ws, bias, out, n2);
    }
}